// Round 23
// baseline (293.726 us; speedup 1.0000x reference)
//
#include <hip/hip_runtime.h>
#include <hip/hip_bf16.h>

#define DI __device__ __forceinline__

typedef __bf16 bf16x8 __attribute__((ext_vector_type(8)));
typedef float  f32x4  __attribute__((ext_vector_type(4)));
typedef float  f32x16 __attribute__((ext_vector_type(16)));
typedef unsigned u32x4 __attribute__((ext_vector_type(4)));

// B=4, T=32, S=256, E=512, H=8, D=64; M = B*T*S = 32768; SCALE = 8.
// Spikes are binary -> bitpacked IN the GEMM kernel (phase 1, LDS-local), so the
// input-BW-bound read (2.7 TB/s roofline) overlaps the MFMA phase across blocks.

DI ushort f2bf(float f) {
  union { float f; unsigned u; } v; v.f = f;
  unsigned r = v.u + 0x7fffu + ((v.u >> 16) & 1u);
  return (ushort)(r >> 16);
}

DI unsigned cvtpk2(float a, float b) {
  unsigned r;
  asm("v_cvt_pk_bf16_f32 %0, %1, %2" : "=v"(r) : "v"(a), "v"(b));
  return r;
}

DI float rcpf(float x) {
  float r;
  asm("v_rcp_f32 %0, %1" : "=v"(r) : "v"(x));
  return r;
}

DI void gload_lds16(const void* g, void* lds) {
  __builtin_amdgcn_global_load_lds(
      (const __attribute__((address_space(1))) unsigned*)g,
      (__attribute__((address_space(3))) unsigned*)lds, 16, 0, 0);
}

#define WAITVM8   asm volatile("s_waitcnt vmcnt(8)" ::: "memory")
#define WAITVM4   asm volatile("s_waitcnt vmcnt(4)" ::: "memory")
#define WAITVM0   asm volatile("s_waitcnt vmcnt(0)" ::: "memory")
#define WAITLGKM0 asm volatile("s_waitcnt lgkmcnt(0)" ::: "memory")
#define SBAR      __builtin_amdgcn_s_barrier()

DI f32x4 zero4() { f32x4 z; z[0] = 0.f; z[1] = 0.f; z[2] = 0.f; z[3] = 0.f; return z; }

DI f32x16 zero16() {
  f32x16 z;
  for (int i = 0; i < 16; i++) z[i] = 0.f;
  return z;
}

union BF8U { ushort u[8]; unsigned d[4]; bf16x8 v; };

// ---------------- weight transpose: W[k][n] f32 -> Wt[n][k] bf16 (4 matrices) --------
__global__ __launch_bounds__(256) void wtrans_kernel(
    const float* __restrict__ W0, const float* __restrict__ W1,
    const float* __restrict__ W2, const float* __restrict__ W3,
    ushort* __restrict__ out) {
  __shared__ float tile[64][65];
  const float* W = blockIdx.z == 0 ? W0 : blockIdx.z == 1 ? W1 : blockIdx.z == 2 ? W2 : W3;
  ushort* o = out + (size_t)blockIdx.z * 512 * 512;
  int k0 = blockIdx.x * 64, n0 = blockIdx.y * 64;
  int tid = threadIdx.x;
#pragma unroll
  for (int i = 0; i < 16; i++) {
    int idx = i * 256 + tid; int r = idx >> 6, c = idx & 63;
    tile[r][c] = W[(size_t)(k0 + r) * 512 + n0 + c];
  }
  __syncthreads();
#pragma unroll
  for (int i = 0; i < 16; i++) {
    int idx = i * 256 + tid; int r = idx >> 6, c = idx & 63;
    o[(size_t)(n0 + r) * 512 + k0 + c] = f2bf(tile[c][r]);
  }
}

// ---------------- FUSED bitpack + Q/K/V projection GEMM ------------------------------
// Block = one 128-row m-panel of one tensor (grid 256 x 3 = 768 = 3 blocks/CU).
// Phase 1: coalesced bitpack of the panel's 256KB fp32 into Bits LDS (8KB) --
//   per 16-row group: chunk c=i*256+tid -> nibble -> Nib LDS; assemble dwords
//   (byte j=sub*8+t covers cols [t*64+sub*8,+8)); 8 groups.
// Phase 2: abits from Bits LDS; r18-proven GEMM core (double-buffer B via
//   global_load_lds, counted vmcnt, LUT expansion) looped over the 4 n-tiles.
// Input read (2.7 TB/s roofline) overlaps other resident blocks' MFMA phase.
__global__ __launch_bounds__(256, 3) void qkv_gemm_kernel(
    const float* __restrict__ q, const float* __restrict__ k,
    const float* __restrict__ v, const ushort* __restrict__ Wt,
    const float* __restrict__ bqp, const float* __restrict__ bkp,
    const float* __restrict__ bvp,
    ushort* __restrict__ Qw, ushort* __restrict__ Kw, ushort* __restrict__ Vt) {
  __shared__ __align__(16) char Blds[32768];   // 2 x 16KB B double buffer
  __shared__ __align__(16) char Bits[8192];    // 128 rows x 64B bitmask
  __shared__ unsigned char Nib[16][128];       // per-group nibble staging
  __shared__ __align__(16) char Lut[128];      // 16 x 8B: nibble -> 4 bf16 {0,1}
  int z = blockIdx.y;
  const float* Af = (z == 0 ? q : z == 1 ? k : v) + (size_t)blockIdx.x * 65536;
  const ushort* Bt = Wt + (size_t)z * 262144;
  const float* bias = z == 0 ? bqp : z == 1 ? bkp : bvp;
  int m0 = blockIdx.x * 128;
  int tid = threadIdx.x, lane = tid & 63, wv = tid >> 6;
  int wm = (wv >> 1) * 64, wn = (wv & 1) * 64;
  int hi4 = lane >> 4;

  if (tid < 16) {
    unsigned n = (unsigned)tid;
    uint2 e;
    e.x = (n & 1u ? 0x3F80u : 0u) | (n & 2u ? 0x3F800000u : 0u);
    e.y = (n & 4u ? 0x3F80u : 0u) | (n & 8u ? 0x3F800000u : 0u);
    *(uint2*)(&Lut[n * 8]) = e;
  }

  // ---- phase 1: bitpack the panel into Bits ----
  int pr = tid >> 4, q16 = tid & 15;
  for (int g = 0; g < 8; g++) {
    unsigned char nibs[8];
#pragma unroll
    for (int i = 0; i < 8; i++) {
      int c = i * 256 + tid;
      u32x4 a = *(const u32x4*)(Af + (size_t)g * 8192 + c * 4);
      nibs[i] = (unsigned char)((a[0] != 0u) | ((a[1] != 0u) << 1) |
                                ((a[2] != 0u) << 2) | ((a[3] != 0u) << 3));
    }
#pragma unroll
    for (int i = 0; i < 8; i++) {
      int c = i * 256 + tid;
      Nib[c >> 7][c & 127] = nibs[i];
    }
    __syncthreads();
    unsigned out = 0;
#pragma unroll
    for (int b = 0; b < 4; b++) {
      int j = q16 * 4 + b;
      int sub = j >> 3, t = j & 7;
      out |= ((unsigned)Nib[pr][t * 16 + sub * 2] |
              ((unsigned)Nib[pr][t * 16 + sub * 2 + 1] << 4)) << (8 * b);
    }
    ((unsigned*)Bits)[(g * 16 + pr) * 16 + q16] = out;
    __syncthreads();
  }

  // ---- abits from Bits LDS ----
  uint2 abits[4][2];
#pragma unroll
  for (int i = 0; i < 4; i++)
#pragma unroll
    for (int ks = 0; ks < 2; ks++)
      abits[i][ks] = *(const uint2*)(Bits + (wm + i * 16 + (lane & 15)) * 64
                                     + (ks * 4 + hi4) * 8);

  auto expandA = [&](int i, int ks, int t) -> bf16x8 {
    unsigned w = t < 4 ? abits[i][ks].x >> (8 * t) : abits[i][ks].y >> (8 * (t - 4));
    unsigned wb = w & 255u;
    uint2 lo = *(const uint2*)(&Lut[(wb & 15u) * 8]);
    uint2 hi = *(const uint2*)(&Lut[(wb >> 4) * 8]);
    BF8U av;
    av.d[0] = lo.x; av.d[1] = lo.y; av.d[2] = hi.x; av.d[3] = hi.y;
    return av.v;
  };

  int n0 = 0;
  auto issueB = [&](int t) {
    char* Bb = Blds + (t & 1) * 16384;
#pragma unroll
    for (int i = 0; i < 4; i++) {
      int c = (wv * 4 + i) * 64 + lane;
      int r = c >> 3, g = (c & 7) ^ (r & 7);
      gload_lds16(Bt + (size_t)(n0 + r) * 512 + t * 64 + g * 8, Bb + (wv * 4 + i) * 1024);
    }
  };

  f32x4 acc[4][4];
  // ---- phase 2: GEMM over the 4 n-tiles ----
  for (int nt = 0; nt < 4; nt++) {
    n0 = nt * 128;
#pragma unroll
    for (int i = 0; i < 4; i++)
#pragma unroll
      for (int j = 0; j < 4; j++) acc[i][j] = zero4();

    issueB(0); issueB(1);
#pragma unroll
    for (int t = 0; t < 8; t++) {
      if (t < 7) { WAITVM4; } else { WAITVM0; }
      SBAR;
      {
        char* Bb = Blds + (t & 1) * 16384;
#pragma unroll
        for (int ks = 0; ks < 2; ks++) {
          bf16x8 a[4], b[4];
#pragma unroll
          for (int i = 0; i < 4; i++) {
            int rb = wn + i * 16 + (lane & 15);
            b[i] = *(const bf16x8*)(Bb + ((rb * 128 + (ks * 4 + hi4) * 16) ^ ((rb & 7) << 4)));
            a[i] = expandA(i, ks, t);
          }
#pragma unroll
          for (int i = 0; i < 4; i++)
#pragma unroll
            for (int j = 0; j < 4; j++)
              acc[i][j] = __builtin_amdgcn_mfma_f32_16x16x32_bf16(a[i], b[j], acc[i][j], 0, 0, 0);
        }
      }
      WAITLGKM0;
      SBAR;
      if (t < 6) issueB(t + 2);
    }

    // epilogue: D col = lane&15, row = (lane>>4)*4 + reg
#pragma unroll
    for (int j = 0; j < 4; j++) {
      int col = n0 + wn + j * 16 + (lane & 15);
      float bv = bias[col];
#pragma unroll
      for (int i = 0; i < 4; i++) {
        int row0 = m0 + wm + i * 16 + (lane >> 4) * 4;
        if (z == 2) {
          int btv = row0 >> 8, s = row0 & 255;
          ushort4 w;
          w.x = f2bf(acc[i][j][0] + bv); w.y = f2bf(acc[i][j][1] + bv);
          w.z = f2bf(acc[i][j][2] + bv); w.w = f2bf(acc[i][j][3] + bv);
          *(ushort4*)(Vt + ((size_t)btv * 512 + col) * 256 + s) = w;
        } else {
          ushort* C = z == 0 ? Qw : Kw;
#pragma unroll
          for (int r = 0; r < 4; r++)
            C[(size_t)(row0 + r) * 512 + col] = f2bf(acc[i][j][r] + bv);
        }
      }
    }
  }
}

// ---------------- output GEMM: bf16 A via global_load_lds, counted vmcnt -------------
__global__ __launch_bounds__(256, 2) void out_gemm_kernel(
    const ushort* __restrict__ A, const ushort* __restrict__ Bt,
    const float* __restrict__ bias, float* __restrict__ C) {
  __shared__ __align__(16) char Alds[32768];
  __shared__ __align__(16) char Blds[32768];
  int bl = ((int)blockIdx.x & 7) * 128 + ((int)blockIdx.x >> 3);
  int m0 = (bl >> 2) * 128, n0 = (bl & 3) * 128;
  int tid = threadIdx.x, lane = tid & 63, wv = tid >> 6;
  int wm = (wv >> 1) * 64, wn = (wv & 1) * 64;

  f32x4 acc[4][4];
#pragma unroll
  for (int i = 0; i < 4; i++)
#pragma unroll
    for (int j = 0; j < 4; j++) acc[i][j] = zero4();

  auto stage = [&](int t) {
    char* Ab = Alds + (t & 1) * 16384;
    char* Bb = Blds + (t & 1) * 16384;
#pragma unroll
    for (int i = 0; i < 4; i++) {
      int c = (wv * 4 + i) * 64 + lane;
      int r = c >> 3, g = (c & 7) ^ (r & 7);
      gload_lds16(A + (size_t)(m0 + r) * 512 + t * 64 + g * 8, Ab + (wv * 4 + i) * 1024);
      gload_lds16(Bt + (size_t)(n0 + r) * 512 + t * 64 + g * 8, Bb + (wv * 4 + i) * 1024);
    }
  };
  auto compute = [&](int t) {
    char* Ab = Alds + (t & 1) * 16384;
    char* Bb = Blds + (t & 1) * 16384;
#pragma unroll
    for (int ks = 0; ks < 2; ks++) {
      bf16x8 a[4], b[4];
#pragma unroll
      for (int i = 0; i < 4; i++) {
        int ra = wm + i * 16 + (lane & 15);
        a[i] = *(const bf16x8*)(Ab + ((ra * 128 + (ks * 4 + (lane >> 4)) * 16) ^ ((ra & 7) << 4)));
        int rb = wn + i * 16 + (lane & 15);
        b[i] = *(const bf16x8*)(Bb + ((rb * 128 + (ks * 4 + (lane >> 4)) * 16) ^ ((rb & 7) << 4)));
      }
#pragma unroll
      for (int i = 0; i < 4; i++)
#pragma unroll
        for (int j = 0; j < 4; j++)
          acc[i][j] = __builtin_amdgcn_mfma_f32_16x16x32_bf16(a[i], b[j], acc[i][j], 0, 0, 0);
    }
  };

  stage(0);
  stage(1);
#pragma unroll
  for (int t = 0; t < 8; t++) {
    if (t < 7) { WAITVM8; } else { WAITVM0; }
    SBAR;
    compute(t);
    WAITLGKM0;
    SBAR;
    if (t < 6) stage(t + 2);
  }

  int lane2 = threadIdx.x & 63;
#pragma unroll
  for (int j = 0; j < 4; j++) {
    int col = n0 + wn + j * 16 + (lane2 & 15);
    float bv = bias[col];
#pragma unroll
    for (int i = 0; i < 4; i++) {
      int row0 = m0 + wm + i * 16 + (lane2 >> 4) * 4;
#pragma unroll
      for (int r = 0; r < 4; r++)
        C[(size_t)(row0 + r) * 512 + col] = acc[i][j][r] + bv;
    }
  }
}

// ---------------- attention: block = (bt,h), 4 waves x 64 q rows -------------------
__global__ __launch_bounds__(256) void attn_kernel(
    const ushort* __restrict__ Q, const ushort* __restrict__ K,
    const ushort* __restrict__ Vt, const float* __restrict__ mw,
    ushort* __restrict__ att) {
  __shared__ __align__(16) char Klds[32768];  // [kt][ds][hi][lq] 16B chunks
  __shared__ __align__(16) char Vlds[32768];  // [kt][ks][df][hi][lq] 16B chunks
  int tid = threadIdx.x, lane = tid & 63, wv = tid >> 6;
  int lq = lane & 31, hi = lane >> 5;
  int b = blockIdx.x;          // 1024 = 128 bt x 8 h
  int h = b & 7, bt = b >> 3;
  const ushort* Qb = Q + ((size_t)bt * 256 + wv * 64) * 512 + h * 64;
  const ushort* Kb = K + ((size_t)bt * 256) * 512 + h * 64;
  const ushort* Vb = Vt + ((size_t)bt * 512 + h * 64) * 256;
  float c0 = mw[h] * mw[8 + h] * 0.125f;

#pragma unroll
  for (int i = 0; i < 8; i++) {
    int ci = (wv * 8 + i) * 64 + lane;
    int l2 = ci & 31, h2 = (ci >> 5) & 1, ds = (ci >> 6) & 3, kt = ci >> 8;
    gload_lds16(Kb + (size_t)(kt * 32 + l2) * 512 + ds * 16 + h2 * 8,
                &Klds[(wv * 8 + i) * 1024]);
  }
  bf16x8 qf[2][4];
#pragma unroll
  for (int qj = 0; qj < 2; qj++)
#pragma unroll
    for (int ds = 0; ds < 4; ds++)
      qf[qj][ds] = *(const bf16x8*)(Qb + (size_t)(qj * 32 + lq) * 512 + ds * 16 + hi * 8);
  __syncthreads();

#pragma unroll
  for (int i = 0; i < 8; i++) {
    int ci = (wv * 8 + i) * 64 + lane;
    int l2 = ci & 31, h2 = (ci >> 5) & 1, df = (ci >> 6) & 1, ks = (ci >> 7) & 1, kt = ci >> 8;
    gload_lds16(Vb + (size_t)(df * 32 + l2) * 256 + kt * 32 + ks * 16 + h2 * 8,
                &Vlds[(wv * 8 + i) * 1024]);
  }

  float mx[2] = {-3.0e38f, -3.0e38f};
#pragma unroll 2
  for (int kt = 0; kt < 8; kt++) {
    bf16x8 kf[4];
#pragma unroll
    for (int ds = 0; ds < 4; ds++)
      kf[ds] = *(const bf16x8*)(&Klds[((kt * 4 + ds) * 2 + hi) * 512 + lq * 16]);
#pragma unroll
    for (int qj = 0; qj < 2; qj++) {
      f32x16 sT = zero16();
#pragma unroll
      for (int ds = 0; ds < 4; ds++)
        sT = __builtin_amdgcn_mfma_f32_32x32x16_bf16(kf[ds], qf[qj][ds], sT, 0, 0, 0);
#pragma unroll
      for (int r = 0; r < 16; r++) mx[qj] = fmaxf(mx[qj], sT[r] * c0);
    }
  }
#pragma unroll
  for (int qj = 0; qj < 2; qj++) mx[qj] = fmaxf(mx[qj], __shfl_xor(mx[qj], 32, 64));
  __syncthreads();   // V staged

  float a5 = 5.f * c0;
  float m5[2] = {5.f * mx[0], 5.f * mx[1]};
  float sm[2] = {0.f, 0.f};
  f32x16 acc[2][2];
  acc[0][0] = zero16(); acc[0][1] = zero16(); acc[1][0] = zero16(); acc[1][1] = zero16();

#pragma unroll 2
  for (int kt = 0; kt < 8; kt++) {
    bf16x8 kf[4], vf[2][2];
#pragma unroll
    for (int ds = 0; ds < 4; ds++)
      kf[ds] = *(const bf16x8*)(&Klds[((kt * 4 + ds) * 2 + hi) * 512 + lq * 16]);
#pragma unroll
    for (int ks = 0; ks < 2; ks++)
#pragma unroll
      for (int df = 0; df < 2; df++)
        vf[ks][df] = *(const bf16x8*)(&Vlds[(((kt * 2 + ks) * 2 + df) * 2 + hi) * 512 + lq * 16]);
#pragma unroll
    for (int qj = 0; qj < 2; qj++) {
      f32x16 sT = zero16();
#pragma unroll
      for (int ds = 0; ds < 4; ds++)
        sT = __builtin_amdgcn_mfma_f32_32x32x16_bf16(kf[ds], qf[qj][ds], sT, 0, 0, 0);
      unsigned pk[8];
#pragma unroll
      for (int i = 0; i < 8; i++) {
        float p0 = rcpf(1.f + __expf(m5[qj] - sT[2 * i] * a5));
        float p1 = rcpf(1.f + __expf(m5[qj] - sT[2 * i + 1] * a5));
        sm[qj] += p0 + p1;
        pk[i] = cvtpk2(p0, p1);
      }
#pragma unroll
      for (int ks = 0; ks < 2; ks++) {
        int bb = ks * 4;
        unsigned sa = (unsigned)__shfl_xor((int)pk[bb + 0], 32, 64);
        unsigned sb = (unsigned)__shfl_xor((int)pk[bb + 1], 32, 64);
        unsigned sc = (unsigned)__shfl_xor((int)pk[bb + 2], 32, 64);
        unsigned sd = (unsigned)__shfl_xor((int)pk[bb + 3], 32, 64);
        BF8U pa;
        pa.d[0] = hi ? sc : pk[bb + 0];
        pa.d[1] = hi ? sd : pk[bb + 1];
        pa.d[2] = hi ? pk[bb + 2] : sa;
        pa.d[3] = hi ? pk[bb + 3] : sb;
#pragma unroll
        for (int df = 0; df < 2; df++)
          acc[qj][df] = __builtin_amdgcn_mfma_f32_32x32x16_bf16(pa.v, vf[ks][df], acc[qj][df], 0, 0, 0);
      }
    }
  }

#pragma unroll
  for (int qj = 0; qj < 2; qj++) sm[qj] += __shfl_xor(sm[qj], 32, 64);
  float rs[2] = {rcpf(sm[0] + 1e-8f), rcpf(sm[1] + 1e-8f)};
#pragma unroll
  for (int qj = 0; qj < 2; qj++) {
#pragma unroll
    for (int r = 0; r < 16; r++) {
      int ql = (r & 3) + 8 * (r >> 2) + 4 * hi;
      float rr = __shfl(rs[qj], ql, 64);
      size_t rowbase = ((size_t)bt * 256 + wv * 64 + qj * 32 + ql) * 512 + h * 64;
#pragma unroll
      for (int df = 0; df < 2; df++)
        att[rowbase + df * 32 + lq] = f2bf(acc[qj][df][r] * rr);
    }
  }
}

extern "C" void kernel_launch(void* const* d_in, const int* in_sizes, int n_in,
                              void* d_out, int out_size, void* d_ws, size_t ws_size,
                              hipStream_t stream) {
  (void)in_sizes; (void)n_in; (void)out_size; (void)ws_size;
  const float* qs  = (const float*)d_in[0];
  const float* ksn = (const float*)d_in[1];
  const float* vsn = (const float*)d_in[2];
  const float* Wq  = (const float*)d_in[3];
  const float* bq  = (const float*)d_in[4];
  const float* Wk  = (const float*)d_in[5];
  const float* bk  = (const float*)d_in[6];
  const float* Wv  = (const float*)d_in[7];
  const float* bv  = (const float*)d_in[8];
  const float* Wo  = (const float*)d_in[9];
  const float* bo  = (const float*)d_in[10];
  const float* mw  = (const float*)d_in[11];
  // d_in[12] = temporal_sync: constant along key axis -> cancels in spike softmax.

  char* ws = (char*)d_ws;
  const size_t SLOT = 33554432u;                   // 32 MiB = 32768*512 bf16
  ushort* Wt = (ushort*)ws;                        // 2 MiB (4 x 512 KiB)
  char*   s0 = ws + (size_t)(8u << 20);
  ushort* Qw = (ushort*)(s0 + 0 * SLOT);
  ushort* Kw = (ushort*)(s0 + 1 * SLOT);
  ushort* Vt = (ushort*)(s0 + 2 * SLOT);
  ushort* Aw = (ushort*)(s0 + 3 * SLOT);

  wtrans_kernel<<<dim3(8, 8, 4), 256, 0, stream>>>(Wq, Wk, Wv, Wo, Wt);
  qkv_gemm_kernel<<<dim3(256, 3), 256, 0, stream>>>(qs, ksn, vsn, Wt, bq, bk, bv,
                                                    Qw, Kw, Vt);
  attn_kernel<<<dim3(1024), 256, 0, stream>>>(Qw, Kw, Vt, mw, Aw);
  out_gemm_kernel<<<dim3(1024), 256, 0, stream>>>(Aw, Wt + 3 * 262144, bo, (float*)d_out);
}

// Round 24
// 180.421 us; speedup vs baseline: 1.6280x; 1.6280x over previous
//
#include <hip/hip_runtime.h>
#include <hip/hip_bf16.h>

#define DI __device__ __forceinline__

typedef __bf16 bf16x8 __attribute__((ext_vector_type(8)));
typedef float  f32x4  __attribute__((ext_vector_type(4)));
typedef float  f32x16 __attribute__((ext_vector_type(16)));
typedef unsigned u32x4 __attribute__((ext_vector_type(4)));

// B=4, T=32, S=256, E=512, H=8, D=64; M = B*T*S = 32768; SCALE = 8.
// Spikes are binary (0.0/1.0) -> packed to bits; A-fragments expanded via LDS LUT.
// r22 configuration (best known: 182us). prep at input-read roofline (~2.7 TB/s,
// 4 structural variants 71-73us). qkv: triple-buffer B, one barrier per K-step.
// r23's bitpack-GEMM fusion thrashed L2 (FETCH 9->280MB) -- reverted.

DI ushort f2bf(float f) {
  union { float f; unsigned u; } v; v.f = f;
  unsigned r = v.u + 0x7fffu + ((v.u >> 16) & 1u);
  return (ushort)(r >> 16);
}

DI unsigned cvtpk2(float a, float b) {  // [bf16(a) | bf16(b)<<16], RNE
  unsigned r;
  asm("v_cvt_pk_bf16_f32 %0, %1, %2" : "=v"(r) : "v"(a), "v"(b));
  return r;
}

DI float rcpf(float x) {
  float r;
  asm("v_rcp_f32 %0, %1" : "=v"(r) : "v"(x));
  return r;
}

DI void gload_lds16(const void* g, void* lds) {
  __builtin_amdgcn_global_load_lds(
      (const __attribute__((address_space(1))) unsigned*)g,
      (__attribute__((address_space(3))) unsigned*)lds, 16, 0, 0);
}

#define WAITVM8   asm volatile("s_waitcnt vmcnt(8)" ::: "memory")
#define WAITVM4   asm volatile("s_waitcnt vmcnt(4)" ::: "memory")
#define WAITVM0   asm volatile("s_waitcnt vmcnt(0)" ::: "memory")
#define WAITLGKM0 asm volatile("s_waitcnt lgkmcnt(0)" ::: "memory")
#define SBAR      __builtin_amdgcn_s_barrier()

DI f32x4 zero4() { f32x4 z; z[0] = 0.f; z[1] = 0.f; z[2] = 0.f; z[3] = 0.f; return z; }

DI f32x16 zero16() {
  f32x16 z;
  for (int i = 0; i < 16; i++) z[i] = 0.f;
  return z;
}

union BF8U { ushort u[8]; unsigned d[4]; bf16x8 v; };

// ---------------- fused prepass: coalesced spike bitpack + weight transpose ----------
// AT ROOFLINE (input-buffer read rate ~2.7 TB/s; 4 structural variants all 71-73us).
__global__ __launch_bounds__(256) void prep_kernel(
    const float* __restrict__ W0, const float* __restrict__ W1,
    const float* __restrict__ W2, const float* __restrict__ W3,
    ushort* __restrict__ wt,
    const float* __restrict__ q, const float* __restrict__ k,
    const float* __restrict__ v, unsigned* __restrict__ bits) {
  __shared__ unsigned char Nib[16][128];       // 2KB: nibble per 4-col group
  int bid = blockIdx.x, tid = threadIdx.x, z = blockIdx.y;
  const float* src = (z == 0 ? q : z == 1 ? k : v) + (size_t)bid * 8192;  // 16 rows

  unsigned char nibs[8];
#pragma unroll
  for (int i = 0; i < 8; i++) {
    int c = i * 256 + tid;                     // chunk 0..2047, coalesced
    u32x4 a = *(const u32x4*)(src + c * 4);
    nibs[i] = (unsigned char)((a[0] != 0u) | ((a[1] != 0u) << 1) |
                              ((a[2] != 0u) << 2) | ((a[3] != 0u) << 3));
  }
#pragma unroll
  for (int i = 0; i < 8; i++) {
    int c = i * 256 + tid;
    Nib[c >> 7][c & 127] = nibs[i];
  }
  __syncthreads();

  int r = tid >> 4, q16 = tid & 15;
  unsigned out = 0;
#pragma unroll
  for (int b = 0; b < 4; b++) {
    int j = q16 * 4 + b;                       // byte index = sub*8 + t
    int sub = j >> 3, t = j & 7;
    unsigned lo = Nib[r][t * 16 + sub * 2];
    unsigned hi = Nib[r][t * 16 + sub * 2 + 1];
    out |= (lo | (hi << 4)) << (8 * b);
  }
  bits[(size_t)z * 524288 + bid * 256 + tid] = out;

  if (z == 0 && bid < 256) {
    __shared__ float tile[64][65];
    int wsel = bid >> 6, tl = bid & 63;
    const float* W = wsel == 0 ? W0 : wsel == 1 ? W1 : wsel == 2 ? W2 : W3;
    ushort* o = wt + (size_t)wsel * 512 * 512;
    int k0 = (tl >> 3) * 64, n0 = (tl & 7) * 64;
#pragma unroll
    for (int i = 0; i < 16; i++) {
      int idx = i * 256 + tid; int rr = idx >> 6, c = idx & 63;
      tile[rr][c] = W[(size_t)(k0 + rr) * 512 + n0 + c];
    }
    __syncthreads();
#pragma unroll
    for (int i = 0; i < 16; i++) {
      int idx = i * 256 + tid; int rr = idx >> 6, c = idx & 63;
      o[(size_t)(n0 + rr) * 512 + k0 + c] = f2bf(tile[c][rr]);
    }
  }
}

// ---------------- fused Q/K/V projection GEMM: triple-buffer B, ONE barrier/step ----
// A == bitmask bytes in regs, expanded via 16x8B LDS LUT (conflict-free). B:
// global_load_lds into a TRIPLE buffer (3x16KB): issueB(t+2) targets buf (t+2)%3
// == (t-1)%3, free since the barrier just passed. Per step: vmcnt(4), SBAR,
// compute, issueB. 48KB+LUT -> 3 blocks/CU.
__global__ __launch_bounds__(256, 3) void qkv_gemm_kernel(
    const unsigned char* __restrict__ Abits, const ushort* __restrict__ Wt,
    const float* __restrict__ bqp, const float* __restrict__ bkp,
    const float* __restrict__ bvp,
    ushort* __restrict__ Qw, ushort* __restrict__ Kw, ushort* __restrict__ Vt) {
  __shared__ __align__(16) char Blds[49152];   // 3 x 16KB
  __shared__ __align__(16) char Lut[128];      // 16 x 8B: nibble -> 4 bf16 {0,1}
  int z = blockIdx.z;
  const unsigned char* Ab8 = Abits + (size_t)z * 2097152;
  const ushort* Bt = Wt + (size_t)z * 262144;
  const float* bias = z == 0 ? bqp : z == 1 ? bkp : bvp;
  int bl = ((int)blockIdx.x & 7) * 128 + ((int)blockIdx.x >> 3);
  int m0 = (bl >> 2) * 128, n0 = (bl & 3) * 128;
  int tid = threadIdx.x, lane = tid & 63, wv = tid >> 6;
  int wm = (wv >> 1) * 64, wn = (wv & 1) * 64;
  int hi4 = lane >> 4;

  if (tid < 16) {
    unsigned n = (unsigned)tid;
    uint2 e;
    e.x = (n & 1u ? 0x3F80u : 0u) | (n & 2u ? 0x3F800000u : 0u);
    e.y = (n & 4u ? 0x3F80u : 0u) | (n & 8u ? 0x3F800000u : 0u);
    *(uint2*)(&Lut[n * 8]) = e;
  }

  f32x4 acc[4][4];
#pragma unroll
  for (int i = 0; i < 4; i++)
#pragma unroll
    for (int j = 0; j < 4; j++) acc[i][j] = zero4();

  // prologue: the 16 bitmask bytes per (i,ks) this lane ever needs
  uint2 abits[4][2];
#pragma unroll
  for (int i = 0; i < 4; i++)
#pragma unroll
    for (int ks = 0; ks < 2; ks++)
      abits[i][ks] = *(const uint2*)(Ab8 + (size_t)(m0 + wm + i * 16 + (lane & 15)) * 64
                                     + (ks * 4 + hi4) * 8);

  auto expandA = [&](int i, int ks, int t) -> bf16x8 {
    unsigned w = t < 4 ? abits[i][ks].x >> (8 * t) : abits[i][ks].y >> (8 * (t - 4));
    unsigned wb = w & 255u;
    uint2 lo = *(const uint2*)(&Lut[(wb & 15u) * 8]);
    uint2 hi = *(const uint2*)(&Lut[(wb >> 4) * 8]);
    BF8U av;
    av.d[0] = lo.x; av.d[1] = lo.y; av.d[2] = hi.x; av.d[3] = hi.y;
    return av.v;
  };
  auto issueB = [&](int t) {  // 4 x global_load_lds dwordx4 per wave
    char* Bb = Blds + (t % 3) * 16384;
#pragma unroll
    for (int i = 0; i < 4; i++) {
      int c = (wv * 4 + i) * 64 + lane;
      int r = c >> 3, g = (c & 7) ^ (r & 7);
      gload_lds16(Bt + (size_t)(n0 + r) * 512 + t * 64 + g * 8, Bb + (wv * 4 + i) * 1024);
    }
  };
  auto compute = [&](int t) {
    char* Bb = Blds + (t % 3) * 16384;
#pragma unroll
    for (int ks = 0; ks < 2; ks++) {
      bf16x8 a[4], b[4];
#pragma unroll
      for (int i = 0; i < 4; i++) {
        int rb = wn + i * 16 + (lane & 15);
        b[i] = *(const bf16x8*)(Bb + ((rb * 128 + (ks * 4 + hi4) * 16) ^ ((rb & 7) << 4)));
        a[i] = expandA(i, ks, t);
      }
#pragma unroll
      for (int i = 0; i < 4; i++)
#pragma unroll
        for (int j = 0; j < 4; j++)
          acc[i][j] = __builtin_amdgcn_mfma_f32_16x16x32_bf16(a[i], b[j], acc[i][j], 0, 0, 0);
    }
  };

  WAITLGKM0;                  // my LUT writes complete before the first rendezvous
  issueB(0); issueB(1);
#pragma unroll
  for (int t = 0; t < 8; t++) {
    if (t < 7) { WAITVM4; } else { WAITVM0; }  // my B(t) stripe landed
    SBAR;                     // all waves: B(t) staged (and buf (t-1)%3 free)
    compute(t);
    if (t < 6) issueB(t + 2); // targets buf (t+2)%3 == (t-1)%3: free since SBAR
  }

  // epilogue: D col = lane&15, row = (lane>>4)*4 + reg
#pragma unroll
  for (int j = 0; j < 4; j++) {
    int col = n0 + wn + j * 16 + (lane & 15);
    float bv = bias[col];
#pragma unroll
    for (int i = 0; i < 4; i++) {
      int row0 = m0 + wm + i * 16 + (lane >> 4) * 4;
      if (z == 2) {
        int btv = row0 >> 8, s = row0 & 255;
        ushort4 w;
        w.x = f2bf(acc[i][j][0] + bv); w.y = f2bf(acc[i][j][1] + bv);
        w.z = f2bf(acc[i][j][2] + bv); w.w = f2bf(acc[i][j][3] + bv);
        *(ushort4*)(Vt + ((size_t)btv * 512 + col) * 256 + s) = w;
      } else {
        ushort* C = z == 0 ? Qw : Kw;
#pragma unroll
        for (int r = 0; r < 4; r++)
          C[(size_t)(row0 + r) * 512 + col] = f2bf(acc[i][j][r] + bv);
      }
    }
  }
}

// ---------------- output GEMM: bf16 A via global_load_lds, counted vmcnt -------------
__global__ __launch_bounds__(256, 2) void out_gemm_kernel(
    const ushort* __restrict__ A, const ushort* __restrict__ Bt,
    const float* __restrict__ bias, float* __restrict__ C) {
  __shared__ __align__(16) char Alds[32768];
  __shared__ __align__(16) char Blds[32768];
  int bl = ((int)blockIdx.x & 7) * 128 + ((int)blockIdx.x >> 3);
  int m0 = (bl >> 2) * 128, n0 = (bl & 3) * 128;
  int tid = threadIdx.x, lane = tid & 63, wv = tid >> 6;
  int wm = (wv >> 1) * 64, wn = (wv & 1) * 64;

  f32x4 acc[4][4];
#pragma unroll
  for (int i = 0; i < 4; i++)
#pragma unroll
    for (int j = 0; j < 4; j++) acc[i][j] = zero4();

  auto stage = [&](int t) {
    char* Ab = Alds + (t & 1) * 16384;
    char* Bb = Blds + (t & 1) * 16384;
#pragma unroll
    for (int i = 0; i < 4; i++) {
      int c = (wv * 4 + i) * 64 + lane;
      int r = c >> 3, g = (c & 7) ^ (r & 7);
      gload_lds16(A + (size_t)(m0 + r) * 512 + t * 64 + g * 8, Ab + (wv * 4 + i) * 1024);
      gload_lds16(Bt + (size_t)(n0 + r) * 512 + t * 64 + g * 8, Bb + (wv * 4 + i) * 1024);
    }
  };
  auto compute = [&](int t) {
    char* Ab = Alds + (t & 1) * 16384;
    char* Bb = Blds + (t & 1) * 16384;
#pragma unroll
    for (int ks = 0; ks < 2; ks++) {
      bf16x8 a[4], b[4];
#pragma unroll
      for (int i = 0; i < 4; i++) {
        int ra = wm + i * 16 + (lane & 15);
        a[i] = *(const bf16x8*)(Ab + ((ra * 128 + (ks * 4 + (lane >> 4)) * 16) ^ ((ra & 7) << 4)));
        int rb = wn + i * 16 + (lane & 15);
        b[i] = *(const bf16x8*)(Bb + ((rb * 128 + (ks * 4 + (lane >> 4)) * 16) ^ ((rb & 7) << 4)));
      }
#pragma unroll
      for (int i = 0; i < 4; i++)
#pragma unroll
        for (int j = 0; j < 4; j++)
          acc[i][j] = __builtin_amdgcn_mfma_f32_16x16x32_bf16(a[i], b[j], acc[i][j], 0, 0, 0);
    }
  };

  stage(0);
  stage(1);
#pragma unroll
  for (int t = 0; t < 8; t++) {
    if (t < 7) { WAITVM8; } else { WAITVM0; }
    SBAR;
    compute(t);
    WAITLGKM0;
    SBAR;
    if (t < 6) stage(t + 2);
  }

  int lane2 = threadIdx.x & 63;
#pragma unroll
  for (int j = 0; j < 4; j++) {
    int col = n0 + wn + j * 16 + (lane2 & 15);
    float bv = bias[col];
#pragma unroll
    for (int i = 0; i < 4; i++) {
      int row0 = m0 + wm + i * 16 + (lane2 >> 4) * 4;
#pragma unroll
      for (int r = 0; r < 4; r++)
        C[(size_t)(row0 + r) * 512 + col] = acc[i][j][r] + bv;
    }
  }
}

// ---------------- attention: block = (bt,h), 4 waves x 64 q rows -------------------
// K and V staged ONCE into LDS via global_load_lds in fragment-read order; V staging
// issued after the K-barrier, drains at the pass-A/pass-B barrier (hidden under pass A).
// Swapped S^T = mfma(K,Q): lane owns q = lane&31; P packed bf16 in-register,
// PV A-frags assembled via shfl_xor(32) + select. temporal_sync cancels.
__global__ __launch_bounds__(256) void attn_kernel(
    const ushort* __restrict__ Q, const ushort* __restrict__ K,
    const ushort* __restrict__ Vt, const float* __restrict__ mw,
    ushort* __restrict__ att) {
  __shared__ __align__(16) char Klds[32768];  // [kt][ds][hi][lq] 16B chunks
  __shared__ __align__(16) char Vlds[32768];  // [kt][ks][df][hi][lq] 16B chunks
  int tid = threadIdx.x, lane = tid & 63, wv = tid >> 6;
  int lq = lane & 31, hi = lane >> 5;
  int b = blockIdx.x;          // 1024 = 128 bt x 8 h
  int h = b & 7, bt = b >> 3;
  const ushort* Qb = Q + ((size_t)bt * 256 + wv * 64) * 512 + h * 64;
  const ushort* Kb = K + ((size_t)bt * 256) * 512 + h * 64;
  const ushort* Vb = Vt + ((size_t)bt * 512 + h * 64) * 256;
  float c0 = mw[h] * mw[8 + h] * 0.125f;

  // stage K: 32 x 1KB instrs across 4 waves, LDS order == fragment-read order
#pragma unroll
  for (int i = 0; i < 8; i++) {
    int ci = (wv * 8 + i) * 64 + lane;
    int l2 = ci & 31, h2 = (ci >> 5) & 1, ds = (ci >> 6) & 3, kt = ci >> 8;
    gload_lds16(Kb + (size_t)(kt * 32 + l2) * 512 + ds * 16 + h2 * 8,
                &Klds[(wv * 8 + i) * 1024]);
  }
  // hoist Q as B-operand fragments (global, drains at first barrier)
  bf16x8 qf[2][4];
#pragma unroll
  for (int qj = 0; qj < 2; qj++)
#pragma unroll
    for (int ds = 0; ds < 4; ds++)
      qf[qj][ds] = *(const bf16x8*)(Qb + (size_t)(qj * 32 + lq) * 512 + ds * 16 + hi * 8);
  __syncthreads();

  // issue V staging now; it drains at the next barrier (hidden under pass A)
#pragma unroll
  for (int i = 0; i < 8; i++) {
    int ci = (wv * 8 + i) * 64 + lane;
    int l2 = ci & 31, h2 = (ci >> 5) & 1, df = (ci >> 6) & 1, ks = (ci >> 7) & 1, kt = ci >> 8;
    gload_lds16(Vb + (size_t)(df * 32 + l2) * 256 + kt * 32 + ks * 16 + h2 * 8,
                &Vlds[(wv * 8 + i) * 1024]);
  }

  // ---- pass A: row max of c0 * (Q.K), K from LDS ----
  float mx[2] = {-3.0e38f, -3.0e38f};
#pragma unroll 2
  for (int kt = 0; kt < 8; kt++) {
    bf16x8 kf[4];
#pragma unroll
    for (int ds = 0; ds < 4; ds++)
      kf[ds] = *(const bf16x8*)(&Klds[((kt * 4 + ds) * 2 + hi) * 512 + lq * 16]);
#pragma unroll
    for (int qj = 0; qj < 2; qj++) {
      f32x16 sT = zero16();
#pragma unroll
      for (int ds = 0; ds < 4; ds++)
        sT = __builtin_amdgcn_mfma_f32_32x32x16_bf16(kf[ds], qf[qj][ds], sT, 0, 0, 0);
#pragma unroll
      for (int r = 0; r < 16; r++) mx[qj] = fmaxf(mx[qj], sT[r] * c0);
    }
  }
#pragma unroll
  for (int qj = 0; qj < 2; qj++) mx[qj] = fmaxf(mx[qj], __shfl_xor(mx[qj], 32, 64));
  __syncthreads();   // V staged

  // ---- pass B: p = sigmoid(5*(s*c0 - mx)); row-sum and P.V ----
  float a5 = 5.f * c0;
  float m5[2] = {5.f * mx[0], 5.f * mx[1]};
  float sm[2] = {0.f, 0.f};
  f32x16 acc[2][2];
  acc[0][0] = zero16(); acc[0][1] = zero16(); acc[1][0] = zero16(); acc[1][1] = zero16();

#pragma unroll 2
  for (int kt = 0; kt < 8; kt++) {
    bf16x8 kf[4], vf[2][2];
#pragma unroll
    for (int ds = 0; ds < 4; ds++)
      kf[ds] = *(const bf16x8*)(&Klds[((kt * 4 + ds) * 2 + hi) * 512 + lq * 16]);
#pragma unroll
    for (int ks = 0; ks < 2; ks++)
#pragma unroll
      for (int df = 0; df < 2; df++)
        vf[ks][df] = *(const bf16x8*)(&Vlds[(((kt * 2 + ks) * 2 + df) * 2 + hi) * 512 + lq * 16]);
#pragma unroll
    for (int qj = 0; qj < 2; qj++) {
      f32x16 sT = zero16();
#pragma unroll
      for (int ds = 0; ds < 4; ds++)
        sT = __builtin_amdgcn_mfma_f32_32x32x16_bf16(kf[ds], qf[qj][ds], sT, 0, 0, 0);
      unsigned pk[8];
#pragma unroll
      for (int i = 0; i < 8; i++) {
        float p0 = rcpf(1.f + __expf(m5[qj] - sT[2 * i] * a5));
        float p1 = rcpf(1.f + __expf(m5[qj] - sT[2 * i + 1] * a5));
        sm[qj] += p0 + p1;
        pk[i] = cvtpk2(p0, p1);
      }
      // reg r holds k = (r&3) + 8*(r>>2) + 4*hi (+32*kt). Assemble A-frags:
#pragma unroll
      for (int ks = 0; ks < 2; ks++) {
        int bb = ks * 4;
        unsigned sa = (unsigned)__shfl_xor((int)pk[bb + 0], 32, 64);
        unsigned sb = (unsigned)__shfl_xor((int)pk[bb + 1], 32, 64);
        unsigned sc = (unsigned)__shfl_xor((int)pk[bb + 2], 32, 64);
        unsigned sd = (unsigned)__shfl_xor((int)pk[bb + 3], 32, 64);
        BF8U pa;
        pa.d[0] = hi ? sc : pk[bb + 0];
        pa.d[1] = hi ? sd : pk[bb + 1];
        pa.d[2] = hi ? pk[bb + 2] : sa;
        pa.d[3] = hi ? pk[bb + 3] : sb;
#pragma unroll
        for (int df = 0; df < 2; df++)
          acc[qj][df] = __builtin_amdgcn_mfma_f32_32x32x16_bf16(pa.v, vf[ks][df], acc[qj][df], 0, 0, 0);
      }
    }
  }

  // ---- epilogue: normalize by row-sum, write att[m][f] bf16 ----
#pragma unroll
  for (int qj = 0; qj < 2; qj++) sm[qj] += __shfl_xor(sm[qj], 32, 64);
  float rs[2] = {rcpf(sm[0] + 1e-8f), rcpf(sm[1] + 1e-8f)};
#pragma unroll
  for (int qj = 0; qj < 2; qj++) {
#pragma unroll
    for (int r = 0; r < 16; r++) {
      int ql = (r & 3) + 8 * (r >> 2) + 4 * hi;
      float rr = __shfl(rs[qj], ql, 64);
      size_t rowbase = ((size_t)bt * 256 + wv * 64 + qj * 32 + ql) * 512 + h * 64;
#pragma unroll
      for (int df = 0; df < 2; df++)
        att[rowbase + df * 32 + lq] = f2bf(acc[qj][df][r] * rr);
    }
  }
}

extern "C" void kernel_launch(void* const* d_in, const int* in_sizes, int n_in,
                              void* d_out, int out_size, void* d_ws, size_t ws_size,
                              hipStream_t stream) {
  (void)in_sizes; (void)n_in; (void)out_size; (void)ws_size;
  const float* qs  = (const float*)d_in[0];
  const float* ksn = (const float*)d_in[1];
  const float* vsn = (const float*)d_in[2];
  const float* Wq  = (const float*)d_in[3];
  const float* bq  = (const float*)d_in[4];
  const float* Wk  = (const float*)d_in[5];
  const float* bk  = (const float*)d_in[6];
  const float* Wv  = (const float*)d_in[7];
  const float* bv  = (const float*)d_in[8];
  const float* Wo  = (const float*)d_in[9];
  const float* bo  = (const float*)d_in[10];
  const float* mw  = (const float*)d_in[11];
  // d_in[12] = temporal_sync: constant along key axis -> cancels in spike softmax.

  char* ws = (char*)d_ws;
  const size_t SLOT = 33554432u;                   // 32 MiB = 32768*512 bf16
  ushort* Wt = (ushort*)ws;                        // 2 MiB (4 x 512 KiB)
  unsigned char* Abits = (unsigned char*)(ws + (size_t)(2u << 20));  // 3 x 2 MiB
  char*   s0 = ws + (size_t)(8u << 20);
  ushort* Qw = (ushort*)(s0 + 0 * SLOT);
  ushort* Kw = (ushort*)(s0 + 1 * SLOT);
  ushort* Vt = (ushort*)(s0 + 2 * SLOT);
  ushort* Aw = (ushort*)(s0 + 3 * SLOT);

  prep_kernel<<<dim3(2048, 3), 256, 0, stream>>>(Wq, Wk, Wv, Wo, Wt, qs, ksn, vsn,
                                                 (unsigned*)Abits);
  qkv_gemm_kernel<<<dim3(1024, 1, 3), 256, 0, stream>>>(Abits, Wt, bq, bk, bv,
                                                        Qw, Kw, Vt);
  attn_kernel<<<dim3(1024), 256, 0, stream>>>(Qw, Kw, Vt, mw, Aw);
  out_gemm_kernel<<<dim3(1024), 256, 0, stream>>>(Aw, Wt + 3 * 262144, bo, (float*)d_out);
}